// Round 21
// baseline (240.015 us; speedup 1.0000x reference)
//
#include <hip/hip_runtime.h>
#include <math.h>

#define BB 32
#define CC 256
#define OO 256
#define HW 56
#define SP (HW*HW)      // 3136
#define KK 4
#define HID 129
#define TEMP 34.0f
#define PROW 58                       // padded rows/cols (1-halo each side)
#define PLANE (PROW*PROW*32)          // u16 per (b,cb) plane = 107648
#define PLANEB (PROW*PROW*64)         // bytes per (b,cb) plane = 215296
#define NSLOT 348                     // 6*58 real slots per staged window
#define QSLOT 350                     // slots incl. 2 dummy pad slots per q-plane
#define QSTRIDE (QSLOT*16)            // 5600 B per q-plane in LDS
#define NPIECE (4*QSLOT)              // 1400 real 16B pieces per x buffer
#define XA_B 8192                     // A-subtile buffer (128o x 32c bf16)
#define XB_B 24576                    // x-window buffer (padded to 1536 pieces)

typedef unsigned short u16;
typedef unsigned int uint32;
typedef __attribute__((ext_vector_type(8))) short bf16x8;
typedef __attribute__((ext_vector_type(4))) float f32x4;

#define WAITVM(n) asm volatile("s_waitcnt vmcnt(" #n ")" ::: "memory")
#define WAITLGKM() asm volatile("s_waitcnt lgkmcnt(0)" ::: "memory")

__device__ __forceinline__ u16 f2bf(float f) {
    union { float f; uint32 u; } v; v.f = f;
    uint32 r = v.u + 0x7FFF + ((v.u >> 16) & 1);
    return (u16)(r >> 16);
}

__device__ __forceinline__ void gload16(const void* g, void* l) {
    __builtin_amdgcn_global_load_lds(
        (const __attribute__((address_space(1))) unsigned int*)g,
        (__attribute__((address_space(3))) unsigned int*)l, 16, 0, 0);
}

// ---------------- Stage 1: fused transpose->bf16 (zero-padded) + mix pooling ----
// float4 loads (4 p per thread per plane) + 256B-contiguous writes (4 slots).
__global__ __launch_bounds__(256) void trans_pool(const float* __restrict__ x,
                                                  u16* __restrict__ xt,
                                                  float* __restrict__ pooled) {
    const int cb = blockIdx.x, b = blockIdx.y;
    const int tid = threadIdx.x;
    const int lane = tid & 63, wave = tid >> 6;
    const float* xp = x + ((size_t)b * CC + cb * 32) * SP;
    const float4* xp4 = (const float4*)xp;      // per plane: 784 float4
    u16* xtb = xt + (size_t)(b * 8 + cb) * PLANE;

    // zero the 228 halo slots
    if (tid < 228) {
        int slot;
        if (tid < 58)       slot = tid;                       // row 0
        else if (tid < 116) slot = 57 * 58 + (tid - 58);      // row 57
        else if (tid < 172) slot = (tid - 116 + 1) * 58;      // col 0, rows 1..56
        else                slot = (tid - 172 + 1) * 58 + 57; // col 57, rows 1..56
        bf16x8 z = {};
        #pragma unroll
        for (int j = 0; j < 4; ++j)
            *(bf16x8*)&xtb[(size_t)slot * 32 + j * 8] = z;
    }

    float psum[32], pmax[32];
    #pragma unroll
    for (int c = 0; c < 32; ++c) { psum[c] = 0.f; pmax[c] = -INFINITY; }

    for (int it = 0; it < 4; ++it) {
        const int idx = it * 256 + tid;         // float4 index, < 784
        const bool v = idx < 784;
        const int ic = v ? idx : 783;
        u16 ob[4][32];
        #pragma unroll
        for (int c = 0; c < 32; ++c) {
            const float4 vv = xp4[(size_t)c * 784 + ic];
            if (v) {
                psum[c] += vv.x + vv.y + vv.z + vv.w;
                pmax[c] = fmaxf(pmax[c], fmaxf(fmaxf(vv.x, vv.y), fmaxf(vv.z, vv.w)));
            }
            ob[0][c] = f2bf(vv.x); ob[1][c] = f2bf(vv.y);
            ob[2][c] = f2bf(vv.z); ob[3][c] = f2bf(vv.w);
        }
        if (v) {
            const int p = idx * 4;              // 56 % 4 == 0 -> same row for p..p+3
            const int slot = (p / 56 + 1) * 58 + (p % 56 + 1);
            #pragma unroll
            for (int j = 0; j < 4; ++j)
                #pragma unroll
                for (int q = 0; q < 4; ++q)
                    *(bf16x8*)&xtb[(size_t)(slot + j) * 32 + q * 8] = *(bf16x8*)&ob[j][q * 8];
        }
    }
    #pragma unroll
    for (int c = 0; c < 32; ++c) {
        #pragma unroll
        for (int off = 32; off >= 1; off >>= 1) {
            psum[c] += __shfl_xor(psum[c], off, 64);
            pmax[c] = fmaxf(pmax[c], __shfl_xor(pmax[c], off, 64));
        }
    }
    __shared__ float ssum[4][32];
    __shared__ float smax[4][32];
    if (lane == 0) {
        #pragma unroll
        for (int c = 0; c < 32; ++c) { ssum[wave][c] = psum[c]; smax[wave][c] = pmax[c]; }
    }
    __syncthreads();
    if (tid < 32) {
        const float s = ssum[0][tid] + ssum[1][tid] + ssum[2][tid] + ssum[3][tid];
        const float m = fmaxf(fmaxf(smax[0][tid], smax[1][tid]),
                              fmaxf(smax[2][tid], smax[3][tid]));
        pooled[b * (2 * CC) + cb * 32 + tid]      = s / (float)SP;
        pooled[b * (2 * CC) + CC + cb * 32 + tid] = m;
    }
}

// ---------------- Stage 2: attention MLP + softmax + agg bias ----------------
__global__ __launch_bounds__(256) void attn_kernel(const float* __restrict__ pooled,
                                                   const float* __restrict__ w1,
                                                   const float* __restrict__ w2,
                                                   const float* __restrict__ b2,
                                                   const float* __restrict__ bias_k,
                                                   float* __restrict__ attn,
                                                   float* __restrict__ agg_b) {
    const int b = blockIdx.x;
    const int tid = threadIdx.x;
    __shared__ float p[2 * CC];
    __shared__ float h[HID];
    __shared__ float a[KK];
    for (int i = tid; i < 2 * CC; i += 256) p[i] = pooled[b * 2 * CC + i];
    __syncthreads();
    if (tid < HID) {
        float s = 0.f;
        const float* w1r = w1 + (size_t)tid * (2 * CC);
        for (int c = 0; c < 2 * CC; ++c) s = fmaf(p[c], w1r[c], s);
        h[tid] = fmaxf(s, 0.f);
    }
    __syncthreads();
    if (tid == 0) {
        float lg[KK];
        float m = -INFINITY;
        for (int k = 0; k < KK; ++k) {
            float s = b2[k];
            for (int i = 0; i < HID; ++i) s = fmaf(h[i], w2[k * HID + i], s);
            lg[k] = s / TEMP;
            m = fmaxf(m, lg[k]);
        }
        float den = 0.f;
        for (int k = 0; k < KK; ++k) { lg[k] = expf(lg[k] - m); den += lg[k]; }
        for (int k = 0; k < KK; ++k) { a[k] = lg[k] / den; attn[b * KK + k] = a[k]; }
    }
    __syncthreads();
    if (tid < OO) {
        float s = 0.f;
        #pragma unroll
        for (int k = 0; k < KK; ++k) s = fmaf(a[k], bias_k[k * OO + tid], s);
        agg_b[b * OO + tid] = s;
    }
}

// ---------------- Stage 2b: aggregate weights -> bf16, wT2 layout (R18/R19 form) ----
// wT2[b][uv][cb][oy] = 4096-u16 subtile [kg][128 ol][8 cl] (contiguous 8KB,
// linear-stageable; conv ds_read = linear 16B runs per quarter-wave).
__global__ __launch_bounds__(512) void agg_kernel(const float* __restrict__ weight,
                                                  const float* __restrict__ attn,
                                                  u16* __restrict__ wT2) {
    const int bx = blockIdx.x;            // 0..127
    const int oy = bx & 1, cb = (bx >> 1) & 7, osub = bx >> 4;
    const int tid = threadIdx.x;
    const int oloc = tid >> 5, cl_ = tid & 31;
    const int o = oy * 128 + osub * 16 + oloc;
    const int c = cb * 32 + cl_;
    const int kg = cl_ >> 3, cl = cl_ & 7;

    __shared__ float at[BB * KK];
    __shared__ u16 tbuf[4][9][4][128];    // 36864 B

    if (tid < BB * KK) at[tid] = attn[tid];

    // dense per-thread weight slice: w[k][uv], 9 consecutive floats per k
    float w[KK][9];
    #pragma unroll
    for (int k = 0; k < KK; ++k) {
        const float* wp = weight + (size_t)((k * OO + o) * CC + c) * 9;
        #pragma unroll
        for (int uv = 0; uv < 9; ++uv) w[k][uv] = wp[uv];
    }

    // store-piece decode (loop-invariant): 4608 dwordx2 pieces per round
    int pbb[9]; size_t goff[9]; int loff[9];
    #pragma unroll
    for (int i = 0; i < 9; ++i) {
        const int p = i * 512 + tid;
        const int bb = p / 1152, q = p % 1152;
        const int uv = q >> 7, pkg = (q >> 5) & 3, dq = q & 31;
        pbb[i] = bb;
        goff[i] = (size_t)(uv * 16 + cb * 2 + oy) * 4096 + pkg * 1024 + osub * 128 + dq * 4;
        loff[i] = ((bb * 9 + uv) * 4 + pkg) * 128 + dq * 4;
    }
    __syncthreads();   // at[] visible

    for (int br = 0; br < 8; ++br) {      // rounds of 4 samples
        #pragma unroll
        for (int bb = 0; bb < 4; ++bb) {
            const int b = br * 4 + bb;
            const float a0 = at[b*KK+0], a1 = at[b*KK+1], a2 = at[b*KK+2], a3 = at[b*KK+3];
            #pragma unroll
            for (int uv = 0; uv < 9; ++uv) {
                const float s = a0*w[0][uv] + a1*w[1][uv] + a2*w[2][uv] + a3*w[3][uv];
                tbuf[bb][uv][kg][oloc * 8 + cl] = f2bf(s);
            }
        }
        __syncthreads();
        #pragma unroll
        for (int i = 0; i < 9; ++i) {
            const int b = br * 4 + pbb[i];
            *(uint2*)(wT2 + (size_t)b * 144 * 4096 + goff[i]) =
                *(const uint2*)((const u16*)tbuf + loff[i]);
        }
        __syncthreads();   // protect tbuf before next round
    }
}

// ---------------- Stage 3: MFMA implicit-GEMM conv — 8-phase, M_rep=4 (R19 form) ----
// Grid 896 (XCD-pinned), 256 thr = 4 waves (2M x 2N), block 128o x 224p, wave
// 64o x 112p (M_rep=4, acc 112 AGPR, launch_bounds(256,2)). 72 K-steps; per
// step ONE raw s_barrier + counted vmcnt (never 0): VM = {2,3,4,4,4,4,3,2,2}.
// A: 3-deep LDS ring, linear staging from contiguous wT2 subtile, ds_read
// [kg][ol][8c] (R19 interior — R20's [ol][kg] variant RAISED conflicts 7.2->11.3M).
// B: x-window dbuf, 6 clamped pieces. Measured: ~117us, MfmaUtil ~44 — ~96% of
// the 16x16-MFMA pipe bound for this shape (224 MFMA x 4.85cyc/CU/phase).
__global__ __launch_bounds__(256, 2) void conv_mfma(const u16* __restrict__ xt,
                                                    const u16* __restrict__ wT2,
                                                    const float* __restrict__ agg_b,
                                                    float* __restrict__ out) {
    const int id   = blockIdx.x;
    const int g    = id >> 3;
    const int b    = (id & 7) + 8 * (g / 28);
    const int tile = g % 28;
    const int px   = tile % 14, oy = tile / 14;
    const int tid  = threadIdx.x;
    const int lane = tid & 63, wave = tid >> 6;   // 0..3
    const int wm = wave & 1, wn = wave >> 1;      // 2M x 2N
    const int l15 = lane & 15, kg = lane >> 4;
    const int p0 = px * 224;

    __shared__ char XA[3][XA_B];   // 24576 B
    __shared__ char XB[2][XB_B];   // 49152 B

    // x stage-piece map (6 pieces/thread, clamped so every wave issues uniformly)
    uint32 soff[6];
    #pragma unroll
    for (int k = 0; k < 6; ++k) {
        int i = k * 256 + tid;
        if (i >= NPIECE) i = NPIECE - 1;
        const int q = i / QSLOT, slot = i % QSLOT;
        soff[k] = (uint32)((px * 232 + slot) * 64 + q * 16);
    }

    // B-read base byte per n-fragment
    int bboff[7];
    #pragma unroll
    for (int nf = 0; nf < 7; ++nf) {
        const int n = wn * 112 + nf * 16 + l15;
        const int S = (n / 56 + 1) * 58 + (n % 56 + 1);
        bboff[nf] = kg * QSTRIDE + S * 16;
    }

    // A ds_read byte within XA buffer: [kg][ol][8c], ol = wm*64 + mf*16 + l15
    int aoff[4];
    #pragma unroll
    for (int mf = 0; mf < 4; ++mf)
        aoff[mf] = kg * 2048 + (wm * 64 + mf * 16 + l15) * 16;

    const char* xgb = (const char*)xt + (size_t)(b * 8) * PLANEB;
    const char* wAb = (const char*)wT2 + (size_t)b * 9 * 8 * 2 * 8192
                     + (size_t)oy * 8192;                       // + (uv*8+cb)*2*8192
    const size_t tb = (size_t)tid * 16;

    f32x4 acc[4][7];
    #pragma unroll
    for (int mf = 0; mf < 4; ++mf)
        #pragma unroll
        for (int nf = 0; nf < 7; ++nf)
            acc[mf][nf] = (f32x4)0.f;

    // prologue: x chunk 0 -> XB[0]; A steps 0,1 -> XA[0],XA[1] (2 gloads each)
    #pragma unroll
    for (int k = 0; k < 6; ++k)
        gload16(xgb + soff[k], &XB[0][k * 4096 + wave * 1024]);
    {
        const char* a0 = wAb;                                   // (0*8+0)*16384
        gload16(a0 + tb,        &XA[0][wave * 1024]);
        gload16(a0 + 4096 + tb, &XA[0][4096 + wave * 1024]);
        const char* a1 = wAb + (size_t)(1 * 8 + 0) * 2 * 8192;
        gload16(a1 + tb,        &XA[1][wave * 1024]);
        gload16(a1 + 4096 + tb, &XA[1][4096 + wave * 1024]);
    }

    for (int cb = 0; cb < 8; ++cb) {
        const char* RB = XB[cb & 1];
        char* WB = XB[(cb & 1) ^ 1];
        const char* xg_next = xgb + (size_t)((cb + 1) & 7) * PLANEB;

        #pragma unroll
        for (int uv = 0; uv < 9; ++uv) {
            // counted wait (2-gload A-steps): VM = {2,3,4,4,4,4,3,2,2}
            if (uv == 1 || uv == 6) WAITVM(3);
            else if (uv >= 2 && uv <= 5) WAITVM(4);
            else WAITVM(2);
            __builtin_amdgcn_s_barrier();

            // ds_read: 4 A-frags + 7 B-frags
            const char* RA = XA[uv % 3];
            bf16x8 av[4];
            #pragma unroll
            for (int mf = 0; mf < 4; ++mf)
                av[mf] = *(const bf16x8*)(RA + aoff[mf]);
            const int dby = ((uv / 3 - 1) * 58 + (uv % 3 - 1)) * 16;
            bf16x8 bv[7];
            #pragma unroll
            for (int nf = 0; nf < 7; ++nf)
                bv[nf] = *(const bf16x8*)(RB + bboff[nf] + dby);

            // issue stages: A for step j+2 (2 gloads; dummy at tail), x at uv<6
            {
                const int uv_s = (uv + 2 < 9) ? uv + 2 : uv - 7;
                const int cb_s = (uv + 2 < 9) ? cb : ((cb + 1) & 7);
                const char* src = wAb + (size_t)(uv_s * 8 + cb_s) * 2 * 8192;
                char* dst = &XA[(uv + 2) % 3][0];
                gload16(src + tb,        dst + wave * 1024);
                gload16(src + 4096 + tb, dst + 4096 + wave * 1024);
            }
            if (uv < 6)
                gload16(xg_next + soff[uv], &WB[uv * 4096 + wave * 1024]);

            WAITLGKM();
            __builtin_amdgcn_sched_barrier(0);
            __builtin_amdgcn_s_setprio(1);
            #pragma unroll
            for (int nf = 0; nf < 7; ++nf) {
                #pragma unroll
                for (int mf = 0; mf < 4; ++mf)
                    acc[mf][nf] = __builtin_amdgcn_mfma_f32_16x16x32_bf16(av[mf], bv[nf], acc[mf][nf], 0, 0, 0);
            }
            __builtin_amdgcn_s_setprio(0);
        }
    }

    // epilogue: D row = kg*4 + r (-> o), col = l15 (-> p)
    const int obase = oy * 128 + wm * 64;
    float* outb = out + (size_t)b * OO * SP;
    #pragma unroll
    for (int mf = 0; mf < 4; ++mf) {
        #pragma unroll
        for (int r = 0; r < 4; ++r) {
            const int o = obase + mf * 16 + kg * 4 + r;
            const float bias = agg_b[b * OO + o];
            #pragma unroll
            for (int nf = 0; nf < 7; ++nf) {
                const int p = p0 + wn * 112 + nf * 16 + l15;
                outb[(size_t)o * SP + p] = acc[mf][nf][r] + bias;
            }
        }
    }
}

extern "C" void kernel_launch(void* const* d_in, const int* in_sizes, int n_in,
                              void* d_out, int out_size, void* d_ws, size_t ws_size,
                              hipStream_t stream) {
    const float* x      = (const float*)d_in[0];
    const float* weight = (const float*)d_in[1];
    const float* bias_k = (const float*)d_in[2];
    const float* w1     = (const float*)d_in[3];
    const float* w2     = (const float*)d_in[4];
    const float* b2     = (const float*)d_in[5];
    float* out = (float*)d_out;

    // workspace: x_t padded bf16 (55.1 MB) | wT2 bf16 (37.75 MB) | fp32 scratch
    u16* x_t = (u16*)d_ws;
    u16* wT2 = x_t + (size_t)BB * 8 * PLANE;
    float* ws_f   = (float*)(wT2 + (size_t)BB * 9 * OO * CC);
    float* pooled = ws_f;
    float* attn   = ws_f + BB * 2 * CC;
    float* agg_b  = attn + BB * KK;

    trans_pool<<<dim3(8, BB), 256, 0, stream>>>(x, x_t, pooled);
    attn_kernel<<<BB, 256, 0, stream>>>(pooled, w1, w2, b2, bias_k, attn, agg_b);
    agg_kernel<<<128, 512, 0, stream>>>(weight, attn, wT2);
    conv_mfma<<<896, 256, 0, stream>>>(x_t, wT2, agg_b, out);
}

// Round 22
// 188.593 us; speedup vs baseline: 1.2727x; 1.2727x over previous
//
#include <hip/hip_runtime.h>
#include <math.h>

#define BB 32
#define CC 256
#define OO 256
#define HW 56
#define SP (HW*HW)      // 3136
#define KK 4
#define HID 129
#define TEMP 34.0f
#define PROW 58                       // padded rows/cols (1-halo each side)
#define PLANE (PROW*PROW*32)          // u16 per (b,cb) plane = 107648
#define PLANEB (PROW*PROW*64)         // bytes per (b,cb) plane = 215296
#define NSLOT 348                     // 6*58 real slots per staged window
#define QSLOT 350                     // slots incl. 2 dummy pad slots per q-plane
#define QSTRIDE (QSLOT*16)            // 5600 B per q-plane in LDS
#define NPIECE (4*QSLOT)              // 1400 real 16B pieces per x buffer
#define XA_B 8192                     // A-subtile buffer (128o x 32c bf16)
#define XB_B 24576                    // x-window buffer (padded to 1536 pieces)

typedef unsigned short u16;
typedef unsigned int uint32;
typedef __attribute__((ext_vector_type(8))) short bf16x8;
typedef __attribute__((ext_vector_type(4))) float f32x4;

#define WAITVM(n) asm volatile("s_waitcnt vmcnt(" #n ")" ::: "memory")
#define WAITLGKM() asm volatile("s_waitcnt lgkmcnt(0)" ::: "memory")

__device__ __forceinline__ u16 f2bf(float f) {
    union { float f; uint32 u; } v; v.f = f;
    uint32 r = v.u + 0x7FFF + ((v.u >> 16) & 1);
    return (u16)(r >> 16);
}

__device__ __forceinline__ void gload16(const void* g, void* l) {
    __builtin_amdgcn_global_load_lds(
        (const __attribute__((address_space(1))) unsigned int*)g,
        (__attribute__((address_space(3))) unsigned int*)l, 16, 0, 0);
}

// ---------------- Stage 1: fused transpose->bf16 (zero-padded) + mix pooling ----
// Scalar form (R14-R20): moves 158MB at ~6.3TB/s -> ~26us, ALREADY HBM-bound.
// (R21's float4 variant spilled registers: ob[4][32]+32 float4 live -> +50us.)
__global__ __launch_bounds__(256) void trans_pool(const float* __restrict__ x,
                                                  u16* __restrict__ xt,
                                                  float* __restrict__ pooled) {
    const int cb = blockIdx.x, b = blockIdx.y;
    const int tid = threadIdx.x;
    const int lane = tid & 63, wave = tid >> 6;
    const float* xp = x + ((size_t)b * CC + cb * 32) * SP;
    u16* xtb = xt + (size_t)(b * 8 + cb) * PLANE;

    // zero the 228 halo slots
    if (tid < 228) {
        int slot;
        if (tid < 58)       slot = tid;                       // row 0
        else if (tid < 116) slot = 57 * 58 + (tid - 58);      // row 57
        else if (tid < 172) slot = (tid - 116 + 1) * 58;      // col 0, rows 1..56
        else                slot = (tid - 172 + 1) * 58 + 57; // col 57, rows 1..56
        bf16x8 z = {};
        #pragma unroll
        for (int j = 0; j < 4; ++j)
            *(bf16x8*)&xtb[(size_t)slot * 32 + j * 8] = z;
    }

    float psum[32], pmax[32];
    #pragma unroll
    for (int c = 0; c < 32; ++c) { psum[c] = 0.f; pmax[c] = -INFINITY; }

    for (int p0 = 0; p0 < SP; p0 += 256) {
        const int p = p0 + tid;
        const bool v = p < SP;
        const int pc = v ? p : (SP - 1);
        u16 ob[32];
        #pragma unroll
        for (int c = 0; c < 32; ++c) {
            const float vv = xp[(size_t)c * SP + pc];
            if (v) { psum[c] += vv; pmax[c] = fmaxf(pmax[c], vv); }
            ob[c] = f2bf(vv);
        }
        if (v) {
            const int slot = (p / 56 + 1) * 58 + (p % 56 + 1);
            #pragma unroll
            for (int j = 0; j < 4; ++j)
                *(bf16x8*)&xtb[(size_t)slot * 32 + j * 8] = *(bf16x8*)&ob[j * 8];
        }
    }
    #pragma unroll
    for (int c = 0; c < 32; ++c) {
        #pragma unroll
        for (int off = 32; off >= 1; off >>= 1) {
            psum[c] += __shfl_xor(psum[c], off, 64);
            pmax[c] = fmaxf(pmax[c], __shfl_xor(pmax[c], off, 64));
        }
    }
    __shared__ float ssum[4][32];
    __shared__ float smax[4][32];
    if (lane == 0) {
        #pragma unroll
        for (int c = 0; c < 32; ++c) { ssum[wave][c] = psum[c]; smax[wave][c] = pmax[c]; }
    }
    __syncthreads();
    if (tid < 32) {
        const float s = ssum[0][tid] + ssum[1][tid] + ssum[2][tid] + ssum[3][tid];
        const float m = fmaxf(fmaxf(smax[0][tid], smax[1][tid]),
                              fmaxf(smax[2][tid], smax[3][tid]));
        pooled[b * (2 * CC) + cb * 32 + tid]      = s / (float)SP;
        pooled[b * (2 * CC) + CC + cb * 32 + tid] = m;
    }
}

// ---------------- Stage 2: attention MLP + softmax + agg bias ----------------
__global__ __launch_bounds__(256) void attn_kernel(const float* __restrict__ pooled,
                                                   const float* __restrict__ w1,
                                                   const float* __restrict__ w2,
                                                   const float* __restrict__ b2,
                                                   const float* __restrict__ bias_k,
                                                   float* __restrict__ attn,
                                                   float* __restrict__ agg_b) {
    const int b = blockIdx.x;
    const int tid = threadIdx.x;
    __shared__ float p[2 * CC];
    __shared__ float h[HID];
    __shared__ float a[KK];
    for (int i = tid; i < 2 * CC; i += 256) p[i] = pooled[b * 2 * CC + i];
    __syncthreads();
    if (tid < HID) {
        float s = 0.f;
        const float* w1r = w1 + (size_t)tid * (2 * CC);
        for (int c = 0; c < 2 * CC; ++c) s = fmaf(p[c], w1r[c], s);
        h[tid] = fmaxf(s, 0.f);
    }
    __syncthreads();
    if (tid == 0) {
        float lg[KK];
        float m = -INFINITY;
        for (int k = 0; k < KK; ++k) {
            float s = b2[k];
            for (int i = 0; i < HID; ++i) s = fmaf(h[i], w2[k * HID + i], s);
            lg[k] = s / TEMP;
            m = fmaxf(m, lg[k]);
        }
        float den = 0.f;
        for (int k = 0; k < KK; ++k) { lg[k] = expf(lg[k] - m); den += lg[k]; }
        for (int k = 0; k < KK; ++k) { a[k] = lg[k] / den; attn[b * KK + k] = a[k]; }
    }
    __syncthreads();
    if (tid < OO) {
        float s = 0.f;
        #pragma unroll
        for (int k = 0; k < KK; ++k) s = fmaf(a[k], bias_k[k * OO + tid], s);
        agg_b[b * OO + tid] = s;
    }
}

// ---------------- Stage 2b: aggregate weights -> bf16, wT2 layout (R18/R19 form) ----
// wT2[b][uv][cb][oy] = 4096-u16 subtile [kg][128 ol][8 cl] (contiguous 8KB,
// linear-stageable; conv ds_read = linear 16B runs per quarter-wave).
__global__ __launch_bounds__(512) void agg_kernel(const float* __restrict__ weight,
                                                  const float* __restrict__ attn,
                                                  u16* __restrict__ wT2) {
    const int bx = blockIdx.x;            // 0..127
    const int oy = bx & 1, cb = (bx >> 1) & 7, osub = bx >> 4;
    const int tid = threadIdx.x;
    const int oloc = tid >> 5, cl_ = tid & 31;
    const int o = oy * 128 + osub * 16 + oloc;
    const int c = cb * 32 + cl_;
    const int kg = cl_ >> 3, cl = cl_ & 7;

    __shared__ float at[BB * KK];
    __shared__ u16 tbuf[4][9][4][128];    // 36864 B

    if (tid < BB * KK) at[tid] = attn[tid];

    // dense per-thread weight slice: w[k][uv], 9 consecutive floats per k
    float w[KK][9];
    #pragma unroll
    for (int k = 0; k < KK; ++k) {
        const float* wp = weight + (size_t)((k * OO + o) * CC + c) * 9;
        #pragma unroll
        for (int uv = 0; uv < 9; ++uv) w[k][uv] = wp[uv];
    }

    // store-piece decode (loop-invariant): 4608 dwordx2 pieces per round
    int pbb[9]; size_t goff[9]; int loff[9];
    #pragma unroll
    for (int i = 0; i < 9; ++i) {
        const int p = i * 512 + tid;
        const int bb = p / 1152, q = p % 1152;
        const int uv = q >> 7, pkg = (q >> 5) & 3, dq = q & 31;
        pbb[i] = bb;
        goff[i] = (size_t)(uv * 16 + cb * 2 + oy) * 4096 + pkg * 1024 + osub * 128 + dq * 4;
        loff[i] = ((bb * 9 + uv) * 4 + pkg) * 128 + dq * 4;
    }
    __syncthreads();   // at[] visible

    for (int br = 0; br < 8; ++br) {      // rounds of 4 samples
        #pragma unroll
        for (int bb = 0; bb < 4; ++bb) {
            const int b = br * 4 + bb;
            const float a0 = at[b*KK+0], a1 = at[b*KK+1], a2 = at[b*KK+2], a3 = at[b*KK+3];
            #pragma unroll
            for (int uv = 0; uv < 9; ++uv) {
                const float s = a0*w[0][uv] + a1*w[1][uv] + a2*w[2][uv] + a3*w[3][uv];
                tbuf[bb][uv][kg][oloc * 8 + cl] = f2bf(s);
            }
        }
        __syncthreads();
        #pragma unroll
        for (int i = 0; i < 9; ++i) {
            const int b = br * 4 + pbb[i];
            *(uint2*)(wT2 + (size_t)b * 144 * 4096 + goff[i]) =
                *(const uint2*)((const u16*)tbuf + loff[i]);
        }
        __syncthreads();   // protect tbuf before next round
    }
}

// ---------------- Stage 3: MFMA implicit-GEMM conv — 8-phase, M_rep=4 (R19 form) ----
// Grid 896 (XCD-pinned), 256 thr = 4 waves (2M x 2N), block 128o x 224p, wave
// 64o x 112p (M_rep=4, acc 112 AGPR, launch_bounds(256,2)). 72 K-steps; per
// step ONE raw s_barrier + counted vmcnt (never 0): VM = {2,3,4,4,4,4,3,2,2}.
// A: 3-deep LDS ring, linear staging from contiguous wT2 subtile, ds_read
// [kg][ol][8c] (R19 interior — R20's [ol][kg] variant RAISED conflicts).
// B: x-window dbuf, 6 clamped pieces. Measured: ~117us, MfmaUtil ~43, stable
// across R19/R20/R21.
__global__ __launch_bounds__(256, 2) void conv_mfma(const u16* __restrict__ xt,
                                                    const u16* __restrict__ wT2,
                                                    const float* __restrict__ agg_b,
                                                    float* __restrict__ out) {
    const int id   = blockIdx.x;
    const int g    = id >> 3;
    const int b    = (id & 7) + 8 * (g / 28);
    const int tile = g % 28;
    const int px   = tile % 14, oy = tile / 14;
    const int tid  = threadIdx.x;
    const int lane = tid & 63, wave = tid >> 6;   // 0..3
    const int wm = wave & 1, wn = wave >> 1;      // 2M x 2N
    const int l15 = lane & 15, kg = lane >> 4;
    const int p0 = px * 224;

    __shared__ char XA[3][XA_B];   // 24576 B
    __shared__ char XB[2][XB_B];   // 49152 B

    // x stage-piece map (6 pieces/thread, clamped so every wave issues uniformly)
    uint32 soff[6];
    #pragma unroll
    for (int k = 0; k < 6; ++k) {
        int i = k * 256 + tid;
        if (i >= NPIECE) i = NPIECE - 1;
        const int q = i / QSLOT, slot = i % QSLOT;
        soff[k] = (uint32)((px * 232 + slot) * 64 + q * 16);
    }

    // B-read base byte per n-fragment
    int bboff[7];
    #pragma unroll
    for (int nf = 0; nf < 7; ++nf) {
        const int n = wn * 112 + nf * 16 + l15;
        const int S = (n / 56 + 1) * 58 + (n % 56 + 1);
        bboff[nf] = kg * QSTRIDE + S * 16;
    }

    // A ds_read byte within XA buffer: [kg][ol][8c], ol = wm*64 + mf*16 + l15
    int aoff[4];
    #pragma unroll
    for (int mf = 0; mf < 4; ++mf)
        aoff[mf] = kg * 2048 + (wm * 64 + mf * 16 + l15) * 16;

    const char* xgb = (const char*)xt + (size_t)(b * 8) * PLANEB;
    const char* wAb = (const char*)wT2 + (size_t)b * 9 * 8 * 2 * 8192
                     + (size_t)oy * 8192;                       // + (uv*8+cb)*2*8192
    const size_t tb = (size_t)tid * 16;

    f32x4 acc[4][7];
    #pragma unroll
    for (int mf = 0; mf < 4; ++mf)
        #pragma unroll
        for (int nf = 0; nf < 7; ++nf)
            acc[mf][nf] = (f32x4)0.f;

    // prologue: x chunk 0 -> XB[0]; A steps 0,1 -> XA[0],XA[1] (2 gloads each)
    #pragma unroll
    for (int k = 0; k < 6; ++k)
        gload16(xgb + soff[k], &XB[0][k * 4096 + wave * 1024]);
    {
        const char* a0 = wAb;                                   // (0*8+0)*16384
        gload16(a0 + tb,        &XA[0][wave * 1024]);
        gload16(a0 + 4096 + tb, &XA[0][4096 + wave * 1024]);
        const char* a1 = wAb + (size_t)(1 * 8 + 0) * 2 * 8192;
        gload16(a1 + tb,        &XA[1][wave * 1024]);
        gload16(a1 + 4096 + tb, &XA[1][4096 + wave * 1024]);
    }

    for (int cb = 0; cb < 8; ++cb) {
        const char* RB = XB[cb & 1];
        char* WB = XB[(cb & 1) ^ 1];
        const char* xg_next = xgb + (size_t)((cb + 1) & 7) * PLANEB;

        #pragma unroll
        for (int uv = 0; uv < 9; ++uv) {
            // counted wait (2-gload A-steps): VM = {2,3,4,4,4,4,3,2,2}
            if (uv == 1 || uv == 6) WAITVM(3);
            else if (uv >= 2 && uv <= 5) WAITVM(4);
            else WAITVM(2);
            __builtin_amdgcn_s_barrier();

            // ds_read: 4 A-frags + 7 B-frags
            const char* RA = XA[uv % 3];
            bf16x8 av[4];
            #pragma unroll
            for (int mf = 0; mf < 4; ++mf)
                av[mf] = *(const bf16x8*)(RA + aoff[mf]);
            const int dby = ((uv / 3 - 1) * 58 + (uv % 3 - 1)) * 16;
            bf16x8 bv[7];
            #pragma unroll
            for (int nf = 0; nf < 7; ++nf)
                bv[nf] = *(const bf16x8*)(RB + bboff[nf] + dby);

            // issue stages: A for step j+2 (2 gloads; dummy at tail), x at uv<6
            {
                const int uv_s = (uv + 2 < 9) ? uv + 2 : uv - 7;
                const int cb_s = (uv + 2 < 9) ? cb : ((cb + 1) & 7);
                const char* src = wAb + (size_t)(uv_s * 8 + cb_s) * 2 * 8192;
                char* dst = &XA[(uv + 2) % 3][0];
                gload16(src + tb,        dst + wave * 1024);
                gload16(src + 4096 + tb, dst + 4096 + wave * 1024);
            }
            if (uv < 6)
                gload16(xg_next + soff[uv], &WB[uv * 4096 + wave * 1024]);

            WAITLGKM();
            __builtin_amdgcn_sched_barrier(0);
            __builtin_amdgcn_s_setprio(1);
            #pragma unroll
            for (int nf = 0; nf < 7; ++nf) {
                #pragma unroll
                for (int mf = 0; mf < 4; ++mf)
                    acc[mf][nf] = __builtin_amdgcn_mfma_f32_16x16x32_bf16(av[mf], bv[nf], acc[mf][nf], 0, 0, 0);
            }
            __builtin_amdgcn_s_setprio(0);
        }
    }

    // epilogue: D row = kg*4 + r (-> o), col = l15 (-> p)
    const int obase = oy * 128 + wm * 64;
    float* outb = out + (size_t)b * OO * SP;
    #pragma unroll
    for (int mf = 0; mf < 4; ++mf) {
        #pragma unroll
        for (int r = 0; r < 4; ++r) {
            const int o = obase + mf * 16 + kg * 4 + r;
            const float bias = agg_b[b * OO + o];
            #pragma unroll
            for (int nf = 0; nf < 7; ++nf) {
                const int p = p0 + wn * 112 + nf * 16 + l15;
                outb[(size_t)o * SP + p] = acc[mf][nf][r] + bias;
            }
        }
    }
}

extern "C" void kernel_launch(void* const* d_in, const int* in_sizes, int n_in,
                              void* d_out, int out_size, void* d_ws, size_t ws_size,
                              hipStream_t stream) {
    const float* x      = (const float*)d_in[0];
    const float* weight = (const float*)d_in[1];
    const float* bias_k = (const float*)d_in[2];
    const float* w1     = (const float*)d_in[3];
    const float* w2     = (const float*)d_in[4];
    const float* b2     = (const float*)d_in[5];
    float* out = (float*)d_out;

    // workspace: x_t padded bf16 (55.1 MB) | wT2 bf16 (37.75 MB) | fp32 scratch
    u16* x_t = (u16*)d_ws;
    u16* wT2 = x_t + (size_t)BB * 8 * PLANE;
    float* ws_f   = (float*)(wT2 + (size_t)BB * 9 * OO * CC);
    float* pooled = ws_f;
    float* attn   = ws_f + BB * 2 * CC;
    float* agg_b  = attn + BB * KK;

    trans_pool<<<dim3(8, BB), 256, 0, stream>>>(x, x_t, pooled);
    attn_kernel<<<BB, 256, 0, stream>>>(pooled, w1, w2, b2, bias_k, attn, agg_b);
    agg_kernel<<<128, 512, 0, stream>>>(weight, attn, wT2);
    conv_mfma<<<896, 256, 0, stream>>>(x_t, wT2, agg_b, out);
}